// Round 1
// 197.540 us; speedup vs baseline: 1.0582x; 1.0582x over previous
//
#include <hip/hip_runtime.h>
#include <cmath>

// Problem constants
#define B_TOTAL 262144
#define D 16
#define TE 3
#define H 64

#define TPB 16                       // b-tiles (of 16 rows) per wave
#define NBX (B_TOTAL / 16 / TPB)     // 1024 blocks in x
#define NBY 4                        // d-groups of 4 (4 waves/block, one d each)

#define LOG2E 1.44269504088896340736f
#define LN2   0.693147180559945309417f

// f16 transpose buffer row stride (f16 elems). 72 = 64+8 pad: breaks pow2 bank
// aliasing; b128 reads stay 16B-aligned.
#define RSH 72
// A-frag staging stride in dwords. 10 (40B): banks 10*lm mod 32 all distinct
// for lm=0..15 -> conflict-free ds_read_b64; 8B alignment holds.
#define ARS 10

typedef _Float16 half8  __attribute__((ext_vector_type(8)));
typedef _Float16 half4  __attribute__((ext_vector_type(4)));
typedef __fp16   fp16x2 __attribute__((ext_vector_type(2)));   // cvt_pkrtz return type
typedef float    f32x4  __attribute__((ext_vector_type(4)));
typedef unsigned int uint32;

// log2-domain softplus: log2(1 + 2^xs). Scale factors pre-folded into weights:
// W1,b1,b2 carry log2e; W3 carries ln2; ln2*log2e==1 so W2 is raw.
__device__ __forceinline__ float sp_log2(float xs) {
    return __builtin_amdgcn_logf(1.0f + __builtin_amdgcn_exp2f(xs));
}
// exact softplus for the final (unscaled) output
__device__ __forceinline__ float softplus_full(float x) {
    float e = __builtin_amdgcn_exp2f(-fabsf(x) * LOG2E);
    return fmaxf(x, 0.0f) + LN2 * __builtin_amdgcn_logf(1.0f + e);
}

// R10: same dataflow as R9+staging, but targeted at VALU-issue cycles:
//  - __launch_bounds__(256,4): measured occupancy is already 4 waves/SIMD;
//    admit it so the allocator gets ~128 combined regs and stops shuttling
//    accumulators/fragments through AGPRs (accvgpr_read/write churn).
//  - b2/b3 ride the MFMA C operand (loop-invariant broadcast regs; D!=C so
//    no copies, no per-tile adds). L1 keeps the k=4 bias-row trick, C=ZC.
//  - f32->f16 via cvt_pkrtz pairs (half the cvt count); hi half stored with
//    ds_write_b16_d16_hi pattern.
//  - final softplus deferred to the flush pass (full-width, 4/thread) instead
//    of 16 exec-masked evaluations per wave in the tile loop.
__global__ __launch_bounds__(256, 4) void DiagonalVariance_kernel(
    const float* __restrict__ t,   // [B, TE]
    const float* __restrict__ y,   // [B, D]
    const float* __restrict__ W1,  // [D, 4, 64]
    const float* __restrict__ b1,  // [D, 64]
    const float* __restrict__ W2,  // [D, 64, 64]
    const float* __restrict__ b2,  // [D, 64]
    const float* __restrict__ W3,  // [D, 64, 1]
    const float* __restrict__ b3,  // [D, 1]
    float* __restrict__ out)       // [B, D]
{
    __shared__ __align__(16) _Float16 tbuf[4 * 16 * RSH];  // 9.2 KB (per-wave slices)
    __shared__ __align__(16) float obuf[TPB * 16 * 4];     // 4 KB: [row_local][dd]
    __shared__ __align__(16) uint32 abuf[256 * ARS];       // 10 KB: [row][{u0_d,u1}x4]

    const int wave = threadIdx.x >> 6;
    const int lane = threadIdx.x & 63;
    const int q    = lane >> 4;
    const int lm   = lane & 15;
    const int d    = blockIdx.y * 4 + wave;
    const bool q0  = (q == 0);

    // ---- cooperative input staging: thread i pre-packs row i's A-frag ----
    {
        const int i    = threadIdx.x;
        const int grow = blockIdx.x * 256 + i;
        const f32x4 yv = *(const f32x4*)(y + grow * D + blockIdx.y * 4);
        const float* tpp = t + grow * TE;
        const float tt0 = tpp[0], tt1 = tpp[1], tt2 = tpp[2];
        const uint32 u1 = __builtin_bit_cast(uint32, __builtin_amdgcn_cvt_pkrtz(tt1, tt2));
        uint32* ab = abuf + i * ARS;
        ab[0] = __builtin_bit_cast(uint32, __builtin_amdgcn_cvt_pkrtz(yv.x, tt0)); ab[1] = u1;
        ab[2] = __builtin_bit_cast(uint32, __builtin_amdgcn_cvt_pkrtz(yv.y, tt0)); ab[3] = u1;
        ab[4] = __builtin_bit_cast(uint32, __builtin_amdgcn_cvt_pkrtz(yv.z, tt0)); ab[5] = u1;
        ab[6] = __builtin_bit_cast(uint32, __builtin_amdgcn_cvt_pkrtz(yv.w, tt0)); ab[7] = u1;
    }

    const float* __restrict__ W1d = W1 + d * (4 * H);
    const float* __restrict__ b1d = b1 + d * H;
    const float* __restrict__ W2d = W2 + d * (H * H);
    const float* __restrict__ b2d = b2 + d * H;
    const float* __restrict__ W3d = W3 + d * H;

    // ---------------- one-time per-wave fragment setup ----------------
    // W2 B-frags (raw): B[n=16nt+lm][k=32ks+8q+j]
    half8 w2f[2][4];
    #pragma unroll
    for (int ks = 0; ks < 2; ++ks)
        #pragma unroll
        for (int nt = 0; nt < 4; ++nt)
            #pragma unroll
            for (int j = 0; j < 8; ++j)
                w2f[ks][nt][j] = (_Float16)W2d[(32 * ks + 8 * q + j) * H + 16 * nt + lm];

    // W1 B-frags for 16x16x16 MFMA: B[n=16nt+lm][k=4q+i], scaled by log2e;
    // bias b1*log2e at k=4 (q1,i=0); rows k>=5 zero (kill A garbage lanes).
    half4 w1f[4];
    #pragma unroll
    for (int nt = 0; nt < 4; ++nt) {
        #pragma unroll
        for (int i = 0; i < 4; ++i) {
            const int h = 16 * nt + lm;
            float v = 0.0f;
            if (q == 0)           v = W1d[i * H + h] * LOG2E;
            if (q == 1 && i == 0) v = b1d[h] * LOG2E;
            w1f[nt][i] = (_Float16)v;
        }
    }

    // W3 B-frag (scaled by ln2), replicated across all n columns.
    half8 w3f[2];
    #pragma unroll
    for (int ks = 0; ks < 2; ++ks)
        #pragma unroll
        for (int j = 0; j < 8; ++j)
            w3f[ks][j] = (_Float16)(W3d[32 * ks + 8 * q + j] * LN2);

    // Loop-invariant MFMA C operands: zero for L1, broadcast b2*log2e for L2
    // (C col = lm -> same value in all 4 row-regs), broadcast b3 for L3.
    const f32x4 ZC = {0.f, 0.f, 0.f, 0.f};
    f32x4 b2c[4];
    #pragma unroll
    for (int nt = 0; nt < 4; ++nt) {
        const float v = b2d[16 * nt + lm] * LOG2E;
        b2c[nt] = (f32x4){v, v, v, v};
    }
    const float b3s = b3[d];
    const f32x4 b3c = {b3s, b3s, b3s, b3s};

    // f16 LDS transpose bases (per-wave slice, immediate offsets per access)
    _Float16* const tb  = tbuf + wave * (16 * RSH);
    _Float16* const twr = tb + (q * 4) * RSH + lm;       // + r*RSH + nt*16
    const _Float16* const trd = tb + lm * RSH + 8 * q;   // + 32*ks

    // staged A-frag base for this wave: + tg*16*ARS per tile (imm offset)
    const uint32* const ard = abuf + lm * ARS + 2 * wave;

    __syncthreads();   // staging visible to all waves

    #pragma unroll 1
    for (int tg = 0; tg < TPB; ++tg) {
        // ---- A-frag from staged LDS: 1 ds_read_b64 + 2 cndmask ----
        const uint32 a0 = ard[tg * 16 * ARS + 0];
        const uint32 a1 = ard[tg * 16 * ARS + 1];
        union { half4 h; uint32 u[2]; } af;
        af.u[0] = q0 ? a0 : 0x00003C00u;   // q1: {1.0h,0} bias row k=4
        af.u[1] = q0 ? a1 : 0u;            // q2/q3 garbage killed by zero B rows

        // ---- layer 1: acc1 = (x*W1 + b1)*log2e, C = ZC (hoisted zero) ----
        f32x4 acc1[4];
        #pragma unroll
        for (int nt = 0; nt < 4; ++nt)
            acc1[nt] = __builtin_amdgcn_mfma_f32_16x16x16f16(af.h, w1f[nt], ZC, 0, 0, 0);

        // ---- softplus (log2 domain) -> f16 LDS transpose, packed cvt ----
        #pragma unroll
        for (int nt = 0; nt < 4; ++nt) {
            const fp16x2 p01 = __builtin_amdgcn_cvt_pkrtz(sp_log2(acc1[nt][0]),
                                                          sp_log2(acc1[nt][1]));
            const fp16x2 p23 = __builtin_amdgcn_cvt_pkrtz(sp_log2(acc1[nt][2]),
                                                          sp_log2(acc1[nt][3]));
            __fp16* const wb = (__fp16*)(twr + nt * 16);
            wb[0 * RSH] = p01.x;
            wb[1 * RSH] = p01.y;   // hi half -> ds_write_b16_d16_hi
            wb[2 * RSH] = p23.x;
            wb[3 * RSH] = p23.y;
        }

        // ---- layer-2 A-frags straight from LDS ----
        half8 a2[2];
        #pragma unroll
        for (int ks = 0; ks < 2; ++ks)
            a2[ks] = *(const half8*)(trd + 32 * ks);

        // ---- layer 2: C = b2 broadcast (no epilogue add) ----
        f32x4 acc2[4];
        #pragma unroll
        for (int nt = 0; nt < 4; ++nt)
            acc2[nt] = __builtin_amdgcn_mfma_f32_16x16x32_f16(a2[0], w2f[0][nt], b2c[nt], 0, 0, 0);
        #pragma unroll
        for (int nt = 0; nt < 4; ++nt)
            acc2[nt] = __builtin_amdgcn_mfma_f32_16x16x32_f16(a2[1], w2f[1][nt], acc2[nt], 0, 0, 0);

        // ---- softplus(acc2) -> same LDS transpose ----
        #pragma unroll
        for (int nt = 0; nt < 4; ++nt) {
            const fp16x2 p01 = __builtin_amdgcn_cvt_pkrtz(sp_log2(acc2[nt][0]),
                                                          sp_log2(acc2[nt][1]));
            const fp16x2 p23 = __builtin_amdgcn_cvt_pkrtz(sp_log2(acc2[nt][2]),
                                                          sp_log2(acc2[nt][3]));
            __fp16* const wb = (__fp16*)(twr + nt * 16);
            wb[0 * RSH] = p01.x;
            wb[1 * RSH] = p01.y;
            wb[2 * RSH] = p23.x;
            wb[3 * RSH] = p23.y;
        }

        half8 a3[2];
        #pragma unroll
        for (int ks = 0; ks < 2; ++ks)
            a3[ks] = *(const half8*)(trd + 32 * ks);

        // ---- layer 3: C = b3 broadcast; every column of D3 = pre-softplus out ----
        f32x4 acc3;
        acc3 = __builtin_amdgcn_mfma_f32_16x16x32_f16(a3[0], w3f[0], b3c, 0, 0, 0);
        acc3 = __builtin_amdgcn_mfma_f32_16x16x32_f16(a3[1], w3f[1], acc3, 0, 0, 0);

        // lane lm<4 takes reg r=lm -> row q*4+lm; all 16 rows covered.
        // Final softplus deferred to the flush pass.
        const float v01 = (lm & 1) ? acc3[1] : acc3[0];
        const float v23 = (lm & 1) ? acc3[3] : acc3[2];
        const float vs  = (lm & 2) ? v23 : v01;
        if (lm < 4)
            obuf[(tg * 16 + q * 4 + lm) * 4 + wave] = vs;
    }

    // Single barrier, then softplus + f32x4 flush: thread i handles row i
    // (256 rows), writing out[(blockIdx.x*256 + i)*16 + blockIdx.y*4 .. +3].
    __syncthreads();
    const int i = threadIdx.x;
    f32x4 v = *(const f32x4*)(obuf + 4 * i);
    v.x = softplus_full(v.x);
    v.y = softplus_full(v.y);
    v.z = softplus_full(v.z);
    v.w = softplus_full(v.w);
    *(f32x4*)(out + (blockIdx.x * 256 + i) * D + blockIdx.y * 4) = v;
}

extern "C" void kernel_launch(void* const* d_in, const int* in_sizes, int n_in,
                              void* d_out, int out_size, void* d_ws, size_t ws_size,
                              hipStream_t stream) {
    const float* t  = (const float*)d_in[0];
    const float* y  = (const float*)d_in[1];
    const float* W1 = (const float*)d_in[2];
    const float* b1 = (const float*)d_in[3];
    const float* W2 = (const float*)d_in[4];
    const float* b2 = (const float*)d_in[5];
    const float* W3 = (const float*)d_in[6];
    const float* b3 = (const float*)d_in[7];
    float* out = (float*)d_out;

    DiagonalVariance_kernel<<<dim3(NBX, NBY), dim3(256), 0, stream>>>(
        t, y, W1, b1, W2, b2, W3, b3, out);
}

// Round 2
// 192.561 us; speedup vs baseline: 1.0856x; 1.0259x over previous
//
#include <hip/hip_runtime.h>
#include <cmath>

// Problem constants
#define B_TOTAL 262144
#define D 16
#define TE 3
#define H 64

#define TPB 16                       // b-tiles (of 16 rows) per wave
#define NBX (B_TOTAL / 16 / TPB)     // 1024 blocks in x
#define NBY 4                        // d-groups of 4 (4 waves/block, one d each)

#define LOG2E 1.44269504088896340736f
#define LN2   0.693147180559945309417f

// f16 transpose buffer row stride (f16 elems). 72 = 64+8 pad: breaks pow2 bank
// aliasing; b128 reads stay 16B-aligned.
#define RSH 72
// A-frag staging stride in dwords. 10 (40B): banks 10*lm mod 32 all distinct
// for lm=0..15 -> conflict-free ds_read_b64; 8B alignment holds.
#define ARS 10

#define OSTRIDE (TPB * 16 * 4)       // one obuf half (floats)

typedef _Float16 half8  __attribute__((ext_vector_type(8)));
typedef _Float16 half4  __attribute__((ext_vector_type(4)));
typedef __fp16   fp16x2 __attribute__((ext_vector_type(2)));   // cvt_pkrtz return type
typedef float    f32x4  __attribute__((ext_vector_type(4)));
typedef unsigned int uint32;

// log2-domain softplus: log2(1 + 2^xs). Scale factors pre-folded into weights:
// W1,b1,b2 carry log2e; W3 carries ln2; ln2*log2e==1 so W2 is raw.
__device__ __forceinline__ float sp_log2(float xs) {
    return __builtin_amdgcn_logf(1.0f + __builtin_amdgcn_exp2f(xs));
}
// exact softplus for the final (unscaled) output
__device__ __forceinline__ float softplus_full(float x) {
    float e = __builtin_amdgcn_exp2f(-fabsf(x) * LOG2E);
    return fmaxf(x, 0.0f) + LN2 * __builtin_amdgcn_logf(1.0f + e);
}

// R11: swapped layer-2 MFMA + VALU layer-3.
//  - A/B fragment layouts of mfma_16x16x32_f16 are mutual transposes, so
//    mfma(A=w2f, B=h1frag) reuses the SAME W2 gather and SAME LDS transpose
//    reads as mfma(h1frag, w2f), but yields acc2[hid_out][batch] (col=batch).
//  - Layer 3 then needs only lane-local math: s = sum_{16 hids/lane}
//    sp(acc2)*W3*ln2, one ds_swizzle xor-16 reduce (q0<->q1, q2<->q3), and a
//    2-half obuf write summed at flush. Removes per tile: 2nd LDS transpose
//    (8 cvt_pk + 16 ds_write + 2 ds_read + full lgkm drain), 2 MFMA, epilogue
//    selects. h2 stays f32 (never quantized).
//  - b2 rides L2's C operand (row-indexed now: C[4q+r]); b3 folded into the
//    reduce init on q0 lanes only.
//  - cross-tile A-frag prefetch hides the ~120cy LDS read latency.
__global__ __launch_bounds__(256, 4) void DiagonalVariance_kernel(
    const float* __restrict__ t,   // [B, TE]
    const float* __restrict__ y,   // [B, D]
    const float* __restrict__ W1,  // [D, 4, 64]
    const float* __restrict__ b1,  // [D, 64]
    const float* __restrict__ W2,  // [D, 64, 64]
    const float* __restrict__ b2,  // [D, 64]
    const float* __restrict__ W3,  // [D, 64, 1]
    const float* __restrict__ b3,  // [D, 1]
    float* __restrict__ out)       // [B, D]
{
    __shared__ __align__(16) _Float16 tbuf[4 * 16 * RSH];   // 9.2 KB (per-wave slices)
    __shared__ __align__(16) float obuf[2 * OSTRIDE];       // 8 KB: [half][row_local][dd]
    __shared__ __align__(16) uint32 abuf[256 * ARS];        // 10 KB: [row][{u0_d,u1}x4]

    const int wave = threadIdx.x >> 6;
    const int lane = threadIdx.x & 63;
    const int q    = lane >> 4;
    const int lm   = lane & 15;
    const int d    = blockIdx.y * 4 + wave;
    const bool q0  = (q == 0);

    // ---- cooperative input staging: thread i pre-packs row i's A-frag ----
    {
        const int i    = threadIdx.x;
        const int grow = blockIdx.x * 256 + i;
        const f32x4 yv = *(const f32x4*)(y + grow * D + blockIdx.y * 4);
        const float* tpp = t + grow * TE;
        const float tt0 = tpp[0], tt1 = tpp[1], tt2 = tpp[2];
        const uint32 u1 = __builtin_bit_cast(uint32, __builtin_amdgcn_cvt_pkrtz(tt1, tt2));
        uint32* ab = abuf + i * ARS;
        ab[0] = __builtin_bit_cast(uint32, __builtin_amdgcn_cvt_pkrtz(yv.x, tt0)); ab[1] = u1;
        ab[2] = __builtin_bit_cast(uint32, __builtin_amdgcn_cvt_pkrtz(yv.y, tt0)); ab[3] = u1;
        ab[4] = __builtin_bit_cast(uint32, __builtin_amdgcn_cvt_pkrtz(yv.z, tt0)); ab[5] = u1;
        ab[6] = __builtin_bit_cast(uint32, __builtin_amdgcn_cvt_pkrtz(yv.w, tt0)); ab[7] = u1;
    }

    const float* __restrict__ W1d = W1 + d * (4 * H);
    const float* __restrict__ b1d = b1 + d * H;
    const float* __restrict__ W2d = W2 + d * (H * H);
    const float* __restrict__ b2d = b2 + d * H;
    const float* __restrict__ W3d = W3 + d * H;

    // ---------------- one-time per-wave fragment setup ----------------
    // W2 fragments (raw): element [k=32ks+8q+j][n=16nt+lm]. Used as the A
    // operand of the swapped L2 MFMA (A-frag of W2^T == B-frag of W2, same
    // register content).
    half8 w2f[2][4];
    #pragma unroll
    for (int ks = 0; ks < 2; ++ks)
        #pragma unroll
        for (int nt = 0; nt < 4; ++nt)
            #pragma unroll
            for (int j = 0; j < 8; ++j)
                w2f[ks][nt][j] = (_Float16)W2d[(32 * ks + 8 * q + j) * H + 16 * nt + lm];

    // W1 B-frags for 16x16x16 MFMA: B[n=16nt+lm][k=4q+i], scaled by log2e;
    // bias b1*log2e at k=4 (q1,i=0); rows k>=5 zero (kill A garbage lanes).
    half4 w1f[4];
    #pragma unroll
    for (int nt = 0; nt < 4; ++nt) {
        #pragma unroll
        for (int i = 0; i < 4; ++i) {
            const int h = 16 * nt + lm;
            float v = 0.0f;
            if (q == 0)           v = W1d[i * H + h] * LOG2E;
            if (q == 1 && i == 0) v = b1d[h] * LOG2E;
            w1f[nt][i] = (_Float16)v;
        }
    }

    // L2 C operand: b2*log2e, row-indexed (swapped output row = hid_out =
    // 16nt + 4q + r). Vector loads, 16B aligned.
    const f32x4 ZC = {0.f, 0.f, 0.f, 0.f};
    f32x4 b2c[4];
    #pragma unroll
    for (int nt = 0; nt < 4; ++nt) {
        f32x4 bv = *(const f32x4*)(b2d + 16 * nt + 4 * q);
        b2c[nt] = (f32x4){bv.x * LOG2E, bv.y * LOG2E, bv.z * LOG2E, bv.w * LOG2E};
    }

    // W3*ln2, row-indexed the same way (hid = 16nt+4q+r), for the VALU L3.
    f32x4 w3l[4];
    #pragma unroll
    for (int nt = 0; nt < 4; ++nt) {
        f32x4 wv = *(const f32x4*)(W3d + 16 * nt + 4 * q);
        w3l[nt] = (f32x4){wv.x * LN2, wv.y * LN2, wv.z * LN2, wv.w * LN2};
    }

    // b3 enters the reduce exactly once: init on q0 lanes only.
    const float sInit = ((lane & 48) == 0) ? b3[d] : 0.0f;

    // f16 LDS transpose bases (per-wave slice, immediate offsets per access)
    _Float16* const tb  = tbuf + wave * (16 * RSH);
    _Float16* const twr = tb + (q * 4) * RSH + lm;       // + r*RSH + nt*16
    const _Float16* const trd = tb + lm * RSH + 8 * q;   // + 32*ks

    // staged A-frag base for this wave: + tg*16*ARS per tile (imm offset)
    const uint32* const ard = abuf + lm * ARS + 2 * wave;

    __syncthreads();   // staging visible to all waves

    // ---- cross-tile A-frag prefetch ----
    uint32 a0n = ard[0];
    uint32 a1n = ard[1];

    #pragma unroll 1
    for (int tg = 0; tg < TPB; ++tg) {
        const uint32 a0 = a0n;
        const uint32 a1 = a1n;
        {   // issue next tile's read now; latency hides under this tile
            const int tn = (tg + 1 < TPB) ? (tg + 1) : tg;
            a0n = ard[tn * 16 * ARS + 0];
            a1n = ard[tn * 16 * ARS + 1];
        }
        union { half4 h; uint32 u[2]; } af;
        af.u[0] = q0 ? a0 : 0x00003C00u;   // q1: {1.0h,0} bias row k=4
        af.u[1] = q0 ? a1 : 0u;            // q2/q3 garbage killed by zero B rows

        // ---- layer 1: acc1 = (x*W1 + b1)*log2e, C = ZC ----
        f32x4 acc1[4];
        #pragma unroll
        for (int nt = 0; nt < 4; ++nt)
            acc1[nt] = __builtin_amdgcn_mfma_f32_16x16x16f16(af.h, w1f[nt], ZC, 0, 0, 0);

        // ---- softplus (log2 domain) -> f16 LDS transpose, packed cvt ----
        #pragma unroll
        for (int nt = 0; nt < 4; ++nt) {
            const fp16x2 p01 = __builtin_amdgcn_cvt_pkrtz(sp_log2(acc1[nt][0]),
                                                          sp_log2(acc1[nt][1]));
            const fp16x2 p23 = __builtin_amdgcn_cvt_pkrtz(sp_log2(acc1[nt][2]),
                                                          sp_log2(acc1[nt][3]));
            __fp16* const wb = (__fp16*)(twr + nt * 16);
            wb[0 * RSH] = p01.x;
            wb[1 * RSH] = p01.y;   // hi half -> ds_write_b16_d16_hi
            wb[2 * RSH] = p23.x;
            wb[3 * RSH] = p23.y;
        }

        // ---- h1^T fragments from LDS (same reads as before; now B operand) ----
        half8 a2[2];
        #pragma unroll
        for (int ks = 0; ks < 2; ++ks)
            a2[ks] = *(const half8*)(trd + 32 * ks);

        // ---- layer 2, SWAPPED: D[hid_out][batch] = W2^T * h1^T + b2 ----
        // A=w2f (same regs as the old B-frag), B=a2 (same LDS reads).
        f32x4 acc2[4];
        #pragma unroll
        for (int nt = 0; nt < 4; ++nt)
            acc2[nt] = __builtin_amdgcn_mfma_f32_16x16x32_f16(w2f[0][nt], a2[0], b2c[nt], 0, 0, 0);
        #pragma unroll
        for (int nt = 0; nt < 4; ++nt)
            acc2[nt] = __builtin_amdgcn_mfma_f32_16x16x32_f16(w2f[1][nt], a2[1], acc2[nt], 0, 0, 0);

        // ---- layer 3 as lane-local VALU: s = b3 + sum sp(acc2)*W3*ln2 ----
        // lane holds hids {16nt+4q+r} for batch column lm.
        float s0 = sInit, s1 = 0.0f;
        #pragma unroll
        for (int nt = 0; nt < 4; ++nt) {
            s0 = fmaf(sp_log2(acc2[nt][0]), w3l[nt][0], s0);
            s1 = fmaf(sp_log2(acc2[nt][1]), w3l[nt][1], s1);
            s0 = fmaf(sp_log2(acc2[nt][2]), w3l[nt][2], s0);
            s1 = fmaf(sp_log2(acc2[nt][3]), w3l[nt][3], s1);
        }
        float s = s0 + s1;
        // xor-16 reduce: q0<->q1 and q2<->q3 (within 32-lane halves).
        const uint32 sw = (uint32)__builtin_amdgcn_ds_swizzle(
            (int)__builtin_bit_cast(uint32, s), 0x401F);
        s += __builtin_bit_cast(float, sw);
        // q0 lanes write half 0 (q0+q1 sum); q2 lanes write half 1 (q2+q3).
        if ((lane & 16) == 0)
            obuf[(lane >> 5) * OSTRIDE + (tg * 16 + lm) * 4 + wave] = s;
    }

    // Single barrier, then sum halves + softplus + f32x4 flush: thread i
    // handles row i, writing out[(blockIdx.x*256+i)*16 + blockIdx.y*4 .. +3].
    __syncthreads();
    const int i = threadIdx.x;
    const f32x4 va = *(const f32x4*)(obuf + 4 * i);
    const f32x4 vb = *(const f32x4*)(obuf + OSTRIDE + 4 * i);
    f32x4 v;
    v.x = softplus_full(va.x + vb.x);
    v.y = softplus_full(va.y + vb.y);
    v.z = softplus_full(va.z + vb.z);
    v.w = softplus_full(va.w + vb.w);
    *(f32x4*)(out + (blockIdx.x * 256 + i) * D + blockIdx.y * 4) = v;
}

extern "C" void kernel_launch(void* const* d_in, const int* in_sizes, int n_in,
                              void* d_out, int out_size, void* d_ws, size_t ws_size,
                              hipStream_t stream) {
    const float* t  = (const float*)d_in[0];
    const float* y  = (const float*)d_in[1];
    const float* W1 = (const float*)d_in[2];
    const float* b1 = (const float*)d_in[3];
    const float* W2 = (const float*)d_in[4];
    const float* b2 = (const float*)d_in[5];
    const float* W3 = (const float*)d_in[6];
    const float* b3 = (const float*)d_in[7];
    float* out = (float*)d_out;

    DiagonalVariance_kernel<<<dim3(NBX, NBY), dim3(256), 0, stream>>>(
        t, y, W1, b1, W2, b2, W3, b3, out);
}

// Round 3
// 188.443 us; speedup vs baseline: 1.1093x; 1.0219x over previous
//
#include <hip/hip_runtime.h>
#include <cmath>

// Problem constants
#define B_TOTAL 262144
#define D 16
#define TE 3
#define H 64

#define TPB 16                       // b-tiles (of 16 rows) per wave
#define NBX (B_TOTAL / 16 / TPB)     // 1024 blocks in x
#define NBY 4                        // d-groups of 4 (4 waves/block, one d each)

#define LOG2E 1.44269504088896340736f
#define LN2   0.693147180559945309417f

// A-frag staging stride in dwords. 10 (40B): banks 10*lm mod 32 all distinct
// for lm=0..15 -> conflict-free ds_read_b64; 8B alignment holds.
#define ARS 10

#define OSTRIDE (TPB * 16 * 4)       // one obuf half (floats)

typedef _Float16 half8  __attribute__((ext_vector_type(8)));
typedef _Float16 half4  __attribute__((ext_vector_type(4)));
typedef __fp16   fp16x2 __attribute__((ext_vector_type(2)));   // cvt_pkrtz return type
typedef float    f32x4  __attribute__((ext_vector_type(4)));
typedef unsigned int uint32;

// log2-domain softplus: log2(1 + 2^xs). Scale factors pre-folded into weights:
// W1,b1,b2 carry log2e; W3 carries ln2; ln2*log2e==1 so W2 is raw.
__device__ __forceinline__ float sp_log2(float xs) {
    return __builtin_amdgcn_logf(1.0f + __builtin_amdgcn_exp2f(xs));
}
// exact softplus for the final (unscaled) output
__device__ __forceinline__ float softplus_full(float x) {
    float e = __builtin_amdgcn_exp2f(-fabsf(x) * LOG2E);
    return fmaxf(x, 0.0f) + LN2 * __builtin_amdgcn_logf(1.0f + e);
}

// R12: fully register-resident dataflow (no LDS transpose at all).
// Key layout identity for mfma_f32_16x16x16f16:
//   D layout  (row=4q+r, col=lm)  ==  B-frag layout (k=4q+i, col=lm).
// So compute BOTH layers swapped:
//   L1: acc1[c] = mfma(A=W1^T(+bias row), B=x^T)   -> D[hid=16c+4q+r][batch=lm]
//   L2: acc2[nt] += mfma_16x16x16(A=W2^T[c][nt], B=softplus(acc1[c]))
// softplus(acc1[c]) IS the L2 B-operand in-lane: no ds_write/ds_read, no lgkm
// drain, no transpose bank conflicts, tbuf deleted. The x B-frag and W1 A-frag
// are bit-identical to the previous A/B registers (A-frag of M == B-frag of
// M^T), so input staging and the k=4 bias-row trick carry over unchanged.
// L2 becomes 16 K=16 MFMAs (same matrix-pipe cycles as 8 K=32 ones).
// L3 stays lane-local VALU + one ds_swizzle reduce (R11).
__global__ __launch_bounds__(256, 4) void DiagonalVariance_kernel(
    const float* __restrict__ t,   // [B, TE]
    const float* __restrict__ y,   // [B, D]
    const float* __restrict__ W1,  // [D, 4, 64]
    const float* __restrict__ b1,  // [D, 64]
    const float* __restrict__ W2,  // [D, 64, 64]
    const float* __restrict__ b2,  // [D, 64]
    const float* __restrict__ W3,  // [D, 64, 1]
    const float* __restrict__ b3,  // [D, 1]
    float* __restrict__ out)       // [B, D]
{
    __shared__ __align__(16) float obuf[2 * OSTRIDE];       // 8 KB: [half][row_local][dd]
    __shared__ __align__(16) uint32 abuf[256 * ARS];        // 10 KB: [row][{u0_d,u1}x4]

    const int wave = threadIdx.x >> 6;
    const int lane = threadIdx.x & 63;
    const int q    = lane >> 4;
    const int lm   = lane & 15;
    const int d    = blockIdx.y * 4 + wave;
    const bool q0  = (q == 0);

    // ---- cooperative input staging: thread i pre-packs row i's x-frag ----
    {
        const int i    = threadIdx.x;
        const int grow = blockIdx.x * 256 + i;
        const f32x4 yv = *(const f32x4*)(y + grow * D + blockIdx.y * 4);
        const float* tpp = t + grow * TE;
        const float tt0 = tpp[0], tt1 = tpp[1], tt2 = tpp[2];
        const uint32 u1 = __builtin_bit_cast(uint32, __builtin_amdgcn_cvt_pkrtz(tt1, tt2));
        uint32* ab = abuf + i * ARS;
        ab[0] = __builtin_bit_cast(uint32, __builtin_amdgcn_cvt_pkrtz(yv.x, tt0)); ab[1] = u1;
        ab[2] = __builtin_bit_cast(uint32, __builtin_amdgcn_cvt_pkrtz(yv.y, tt0)); ab[3] = u1;
        ab[4] = __builtin_bit_cast(uint32, __builtin_amdgcn_cvt_pkrtz(yv.z, tt0)); ab[5] = u1;
        ab[6] = __builtin_bit_cast(uint32, __builtin_amdgcn_cvt_pkrtz(yv.w, tt0)); ab[7] = u1;
    }

    const float* __restrict__ W1d = W1 + d * (4 * H);
    const float* __restrict__ b1d = b1 + d * H;
    const float* __restrict__ W2d = W2 + d * (H * H);
    const float* __restrict__ b2d = b2 + d * H;
    const float* __restrict__ W3d = W3 + d * H;

    // ---------------- one-time per-wave fragment setup ----------------
    // W1 as L1 A-operand: A[row=hid(16nt+lm)][k=4q+i] = W1[k][hid]*log2e,
    // bias b1*log2e at k=4 (q1,i=0); k>=5 rows zero (kill x garbage lanes).
    // (Bit-identical registers to the old B-frag of W1.)
    half4 w1f[4];
    #pragma unroll
    for (int nt = 0; nt < 4; ++nt) {
        #pragma unroll
        for (int i = 0; i < 4; ++i) {
            const int h = 16 * nt + lm;
            float v = 0.0f;
            if (q == 0)           v = W1d[i * H + h] * LOG2E;
            if (q == 1 && i == 0) v = b1d[h] * LOG2E;
            w1f[nt][i] = (_Float16)v;
        }
    }

    // W2 as L2 A-operand, K-chunked: w2a[c][nt] lane(q,lm) holds
    // A[row=hid_out=16nt+lm][k=16c+4q+i] = W2[k_in][hid_out] (raw).
    half4 w2a[4][4];
    #pragma unroll
    for (int c = 0; c < 4; ++c)
        #pragma unroll
        for (int nt = 0; nt < 4; ++nt)
            #pragma unroll
            for (int i = 0; i < 4; ++i)
                w2a[c][nt][i] = (_Float16)W2d[(16 * c + 4 * q + i) * H + 16 * nt + lm];

    // L2 C operand: b2*log2e, row-indexed (output row = hid_out = 16nt+4q+r).
    const f32x4 ZC = {0.f, 0.f, 0.f, 0.f};
    f32x4 b2c[4];
    #pragma unroll
    for (int nt = 0; nt < 4; ++nt) {
        f32x4 bv = *(const f32x4*)(b2d + 16 * nt + 4 * q);
        b2c[nt] = (f32x4){bv.x * LOG2E, bv.y * LOG2E, bv.z * LOG2E, bv.w * LOG2E};
    }

    // W3*ln2, row-indexed the same way (hid = 16nt+4q+r), for the VALU L3.
    f32x4 w3l[4];
    #pragma unroll
    for (int nt = 0; nt < 4; ++nt) {
        f32x4 wv = *(const f32x4*)(W3d + 16 * nt + 4 * q);
        w3l[nt] = (f32x4){wv.x * LN2, wv.y * LN2, wv.z * LN2, wv.w * LN2};
    }

    // b3 enters the reduce exactly once: init on q0 lanes only.
    const float sInit = ((lane & 48) == 0) ? b3[d] : 0.0f;

    // staged x-frag base for this wave: + tg*16*ARS per tile (imm offset)
    const uint32* const ard = abuf + lm * ARS + 2 * wave;

    __syncthreads();   // staging visible to all waves

    // ---- cross-tile x-frag prefetch ----
    uint32 a0n = ard[0];
    uint32 a1n = ard[1];

    #pragma unroll 1
    for (int tg = 0; tg < TPB; ++tg) {
        const uint32 a0 = a0n;
        const uint32 a1 = a1n;
        {   // issue next tile's read now; latency hides under this tile
            const int tn = (tg + 1 < TPB) ? (tg + 1) : tg;
            a0n = ard[tn * 16 * ARS + 0];
            a1n = ard[tn * 16 * ARS + 1];
        }
        union { half4 h; uint32 u[2]; } af;
        af.u[0] = q0 ? a0 : 0x00003C00u;   // q1: {1.0h,0} bias row k=4
        af.u[1] = q0 ? a1 : 0u;            // q2/q3 garbage killed by zero A rows

        // ---- layer 1, swapped: acc1[c] = D[hid=16c+4q+r][batch=lm] ----
        f32x4 acc1[4];
        #pragma unroll
        for (int c = 0; c < 4; ++c)
            acc1[c] = __builtin_amdgcn_mfma_f32_16x16x16f16(w1f[c], af.h, ZC, 0, 0, 0);

        // ---- softplus -> f16 B-frags, in-lane (no LDS!) ----
        union { half4 h; uint32 u[2]; } hb[4];
        #pragma unroll
        for (int c = 0; c < 4; ++c) {
            hb[c].u[0] = __builtin_bit_cast(uint32,
                __builtin_amdgcn_cvt_pkrtz(sp_log2(acc1[c][0]), sp_log2(acc1[c][1])));
            hb[c].u[1] = __builtin_bit_cast(uint32,
                __builtin_amdgcn_cvt_pkrtz(sp_log2(acc1[c][2]), sp_log2(acc1[c][3])));
        }

        // ---- layer 2, swapped + K-chunked: acc2[nt] over c ----
        f32x4 acc2[4];
        #pragma unroll
        for (int nt = 0; nt < 4; ++nt)
            acc2[nt] = __builtin_amdgcn_mfma_f32_16x16x16f16(w2a[0][nt], hb[0].h, b2c[nt], 0, 0, 0);
        #pragma unroll
        for (int c = 1; c < 4; ++c)
            #pragma unroll
            for (int nt = 0; nt < 4; ++nt)
                acc2[nt] = __builtin_amdgcn_mfma_f32_16x16x16f16(w2a[c][nt], hb[c].h, acc2[nt], 0, 0, 0);

        // ---- layer 3 as lane-local VALU: s = b3 + sum sp(acc2)*W3*ln2 ----
        // lane holds hids {16nt+4q+r} for batch column lm.
        float s0 = sInit, s1 = 0.0f;
        #pragma unroll
        for (int nt = 0; nt < 4; ++nt) {
            s0 = fmaf(sp_log2(acc2[nt][0]), w3l[nt][0], s0);
            s1 = fmaf(sp_log2(acc2[nt][1]), w3l[nt][1], s1);
            s0 = fmaf(sp_log2(acc2[nt][2]), w3l[nt][2], s0);
            s1 = fmaf(sp_log2(acc2[nt][3]), w3l[nt][3], s1);
        }
        float s = s0 + s1;
        // xor-16 reduce: q0<->q1 and q2<->q3 (within 32-lane halves).
        const uint32 sw = (uint32)__builtin_amdgcn_ds_swizzle(
            (int)__builtin_bit_cast(uint32, s), 0x401F);
        s += __builtin_bit_cast(float, sw);
        // q0 lanes write half 0 (q0+q1 sum); q2 lanes write half 1 (q2+q3).
        if ((lane & 16) == 0)
            obuf[(lane >> 5) * OSTRIDE + (tg * 16 + lm) * 4 + wave] = s;
    }

    // Single barrier, then sum halves + softplus + f32x4 flush: thread i
    // handles row i, writing out[(blockIdx.x*256+i)*16 + blockIdx.y*4 .. +3].
    __syncthreads();
    const int i = threadIdx.x;
    const f32x4 va = *(const f32x4*)(obuf + 4 * i);
    const f32x4 vb = *(const f32x4*)(obuf + OSTRIDE + 4 * i);
    f32x4 v;
    v.x = softplus_full(va.x + vb.x);
    v.y = softplus_full(va.y + vb.y);
    v.z = softplus_full(va.z + vb.z);
    v.w = softplus_full(va.w + vb.w);
    *(f32x4*)(out + (blockIdx.x * 256 + i) * D + blockIdx.y * 4) = v;
}

extern "C" void kernel_launch(void* const* d_in, const int* in_sizes, int n_in,
                              void* d_out, int out_size, void* d_ws, size_t ws_size,
                              hipStream_t stream) {
    const float* t  = (const float*)d_in[0];
    const float* y  = (const float*)d_in[1];
    const float* W1 = (const float*)d_in[2];
    const float* b1 = (const float*)d_in[3];
    const float* W2 = (const float*)d_in[4];
    const float* b2 = (const float*)d_in[5];
    const float* W3 = (const float*)d_in[6];
    const float* b3 = (const float*)d_in[7];
    float* out = (float*)d_out;

    DiagonalVariance_kernel<<<dim3(NBX, NBY), dim3(256), 0, stream>>>(
        t, y, W1, b1, W2, b2, W3, b3, out);
}